// Round 1
// baseline (767.633 us; speedup 1.0000x reference)
//
#include <hip/hip_runtime.h>
#include <cstdio>
#include <cstdint>

#define TOKS 4096
#define DMODEL 1024
#define DFF 4096
#define NEXP 8

typedef __bf16 bf16_8 __attribute__((ext_vector_type(8)));
typedef float f32x4 __attribute__((ext_vector_type(4)));
typedef __attribute__((address_space(1))) const void* gptr_t;
typedef __attribute__((address_space(3))) void* lptr_t;

__device__ __forceinline__ unsigned short f2bf(float f) {
  unsigned int u = __builtin_bit_cast(unsigned int, f);
  u += 0x7FFFu + ((u >> 16) & 1u);
  return (unsigned short)(u >> 16);
}

// ---------------- transpose + cast fp32 [R][C] -> bf16 [C][R], per-expert (blockIdx.y) ----
__global__ __launch_bounds__(256) void transpose_cast_k(const float* __restrict__ in,
                                                        unsigned short* __restrict__ out,
                                                        int R, int C) {
  __shared__ float tile[64][65];
  const float* inm = in + (size_t)blockIdx.y * R * C;
  unsigned short* outm = out + (size_t)blockIdx.y * R * C;
  int tcn = C >> 6;
  int tr = blockIdx.x / tcn, tc = blockIdx.x % tcn;
  int r0 = tr << 6, c0 = tc << 6;
  int tid = threadIdx.x;
  int lr = tid >> 6, lc = tid & 63;
#pragma unroll
  for (int i = 0; i < 16; ++i)
    tile[lr + 4 * i][lc] = inm[(size_t)(r0 + lr + 4 * i) * C + c0 + lc];
  __syncthreads();
#pragma unroll
  for (int i = 0; i < 8; ++i) {
    int row = (tid >> 5) + i * 8;  // out-row (c index) within tile
    int colu = tid & 31;           // uint column (2 bf16)
    float f0 = tile[colu * 2][row];
    float f1 = tile[colu * 2 + 1][row];
    unsigned int u = (unsigned int)f2bf(f0) | ((unsigned int)f2bf(f1) << 16);
    *(unsigned int*)(outm + (size_t)(c0 + row) * R + r0 + colu * 2) = u;
  }
}

// ---------------- cast x fp32 -> bf16 (vectorized) ----------------
__global__ __launch_bounds__(256) void cast_x_k(const float* __restrict__ x,
                                                unsigned short* __restrict__ xb) {
  int i = blockIdx.x * 256 + threadIdx.x;  // exactly TOKS*DMODEL/4 threads
  float4 f = ((const float4*)x)[i];
  ushort4 u;
  u.x = f2bf(f.x); u.y = f2bf(f.y); u.z = f2bf(f.z); u.w = f2bf(f.w);
  ((ushort4*)xb)[i] = u;
}

// ---------------- router: logits -> top2 -> probs -> expert lists ----------------
__global__ __launch_bounds__(256) void router_k(const float* __restrict__ x,
                                                const float* __restrict__ Wr,
                                                const float* __restrict__ br,
                                                int* __restrict__ cnt,
                                                int* __restrict__ list,
                                                float* __restrict__ plist) {
  int t = blockIdx.x * 4 + (threadIdx.x >> 6);
  int lane = threadIdx.x & 63;
  float a[NEXP];
#pragma unroll
  for (int e = 0; e < NEXP; ++e) a[e] = 0.f;
  const float* xr = x + (size_t)t * DMODEL;
  for (int i = lane; i < DMODEL; i += 64) {
    float xv = xr[i];
    const float* wr = Wr + (size_t)i * NEXP;
#pragma unroll
    for (int e = 0; e < NEXP; ++e) a[e] += xv * wr[e];
  }
#pragma unroll
  for (int off = 32; off > 0; off >>= 1) {
#pragma unroll
    for (int e = 0; e < NEXP; ++e) a[e] += __shfl_xor(a[e], off);
  }
  if (lane == 0) {
#pragma unroll
    for (int e = 0; e < NEXP; ++e) a[e] += br[e];
    int i0 = 0; float m0 = a[0];
#pragma unroll
    for (int e = 1; e < NEXP; ++e) if (a[e] > m0) { m0 = a[e]; i0 = e; }
    int i1 = -1; float m1 = -1e30f;
#pragma unroll
    for (int e = 0; e < NEXP; ++e) if (e != i0 && a[e] > m1) { m1 = a[e]; i1 = e; }
    float tt = expf(m1 - m0);
    float p0 = 1.f / (1.f + tt);
    float p1 = 1.f - p0;
    int pos0 = atomicAdd(&cnt[i0], 1);
    list[i0 * TOKS + pos0] = t; plist[i0 * TOKS + pos0] = p0;
    int pos1 = atomicAdd(&cnt[i1], 1);
    list[i1 * TOKS + pos1] = t; plist[i1 * TOKS + pos1] = p1;
  }
}

__global__ void offsets_k(const int* __restrict__ cnt, int* __restrict__ off) {
  if (threadIdx.x == 0) {
    int s = 0;
    for (int e = 0; e < NEXP; ++e) { off[e] = s; s += cnt[e]; }
    off[NEXP] = s;
  }
}

// ---------------- grouped GEMM, 128x128 tile, BK=64, bf16 MFMA 16x16x32 ----------------
// MODE 0: A = xb rows gathered via list  [K=1024], B = W1t [DFF][1024], out: h=relu(.+b1) bf16
// MODE 1: A = h rows (compact slots)     [K=4096], B = W2t [DMODEL][4096], out: atomicAdd p*(.+b2)
template <int MODE>
__global__ __launch_bounds__(256) void moe_gemm_k(
    const unsigned short* __restrict__ Abase, const unsigned short* __restrict__ Bbase,
    const float* __restrict__ bias, const int* __restrict__ cnt, const int* __restrict__ off,
    const int* __restrict__ list, const float* __restrict__ plist,
    unsigned short* __restrict__ Hout, float* __restrict__ Out) {
  constexpr int K = (MODE == 0) ? DMODEL : DFF;
  constexpr int NN = (MODE == 0) ? DFF : DMODEL;
  const int e = blockIdx.z;
  const int ce = cnt[e];
  const int m0 = blockIdx.y * 128;
  if (m0 >= ce) return;                    // empty tile (uniform) -> cheap exit
  const int rem = ce - m0;                 // >= 1
  const int n0 = blockIdx.x * 128;
  const int oe = off[e];

  __shared__ unsigned short As[8192];      // 128 rows x 64 k, XOR-swizzled 16B slots
  __shared__ unsigned short Bs[8192];

  const int tid = threadIdx.x;
  const int lane = tid & 63;
  const int w = tid >> 6;
  const int wm = w >> 1, wn = w & 1;

  const unsigned short* Bm = Bbase + (size_t)e * NN * K;
  // staging: physical 16B slot s = c*256+tid; row = s>>3; logical k-group = (s&7)^(row&7)
  const int g = (tid & 7) ^ ((tid >> 3) & 7);

  size_t a_src[4], b_src[4];
#pragma unroll
  for (int c = 0; c < 4; ++c) {
    int row = c * 32 + (tid >> 3);
    int rr = row < rem ? row : 0;          // clamp padding rows to a valid row
    size_t arow;
    if (MODE == 0) arow = (size_t)list[e * TOKS + m0 + rr];
    else           arow = (size_t)(oe + m0 + rr);
    a_src[c] = arow * K + g * 8;
    b_src[c] = (size_t)(n0 + row) * K + g * 8;
  }

  f32x4 acc[4][4];
#pragma unroll
  for (int i = 0; i < 4; ++i)
#pragma unroll
    for (int j = 0; j < 4; ++j) acc[i][j] = (f32x4){0.f, 0.f, 0.f, 0.f};

  for (int k0 = 0; k0 < K; k0 += 64) {
    __syncthreads();                       // previous tile's reads done
#pragma unroll
    for (int c = 0; c < 4; ++c) {
      __builtin_amdgcn_global_load_lds((gptr_t)(Abase + a_src[c] + k0),
                                       (lptr_t)&As[(c * 256 + w * 64) * 8], 16, 0, 0);
      __builtin_amdgcn_global_load_lds((gptr_t)(Bm + b_src[c] + k0),
                                       (lptr_t)&Bs[(c * 256 + w * 64) * 8], 16, 0, 0);
    }
    __syncthreads();                       // compiler drains vmcnt before barrier
#pragma unroll
    for (int kk = 0; kk < 2; ++kk) {
      bf16_8 av[4], bv[4];
#pragma unroll
      for (int fr = 0; fr < 4; ++fr) {
        int row = wm * 64 + fr * 16 + (lane & 15);
        int slot = row * 8 + ((kk * 4 + (lane >> 4)) ^ (row & 7));
        av[fr] = *(const bf16_8*)&As[slot * 8];
      }
#pragma unroll
      for (int fc = 0; fc < 4; ++fc) {
        int row = wn * 64 + fc * 16 + (lane & 15);
        int slot = row * 8 + ((kk * 4 + (lane >> 4)) ^ (row & 7));
        bv[fc] = *(const bf16_8*)&Bs[slot * 8];
      }
#pragma unroll
      for (int fr = 0; fr < 4; ++fr)
#pragma unroll
        for (int fc = 0; fc < 4; ++fc)
          acc[fr][fc] = __builtin_amdgcn_mfma_f32_16x16x32_bf16(av[fr], bv[fc],
                                                                acc[fr][fc], 0, 0, 0);
    }
  }

  if (MODE == 0) {
    const float* be = bias + (size_t)e * NN + n0;
#pragma unroll
    for (int fr = 0; fr < 4; ++fr) {
#pragma unroll
      for (int j = 0; j < 4; ++j) {
        int row = wm * 64 + fr * 16 + (lane >> 4) * 4 + j;
        if (row < rem) {
          unsigned short* hr = Hout + (size_t)(oe + m0 + row) * DFF + n0;
#pragma unroll
          for (int fc = 0; fc < 4; ++fc) {
            int col = wn * 64 + fc * 16 + (lane & 15);
            float v = acc[fr][fc][j] + be[col];
            hr[col] = f2bf(fmaxf(v, 0.f));
          }
        }
      }
    }
  } else {
    const float* be = bias + (size_t)e * NN + n0;
#pragma unroll
    for (int fr = 0; fr < 4; ++fr) {
#pragma unroll
      for (int j = 0; j < 4; ++j) {
        int row = wm * 64 + fr * 16 + (lane >> 4) * 4 + j;
        if (row < rem) {
          int tok = list[e * TOKS + m0 + row];
          float p = plist[e * TOKS + m0 + row];
          float* orow = Out + (size_t)tok * DMODEL + n0;
#pragma unroll
          for (int fc = 0; fc < 4; ++fc) {
            int col = wn * 64 + fc * 16 + (lane & 15);
            atomicAdd(&orow[col], p * (acc[fr][fc][j] + be[col]));
          }
        }
      }
    }
  }
}

extern "C" void kernel_launch(void* const* d_in, const int* in_sizes, int n_in,
                              void* d_out, int out_size, void* d_ws, size_t ws_size,
                              hipStream_t stream) {
  const float* x  = (const float*)d_in[0];
  const float* Wr = (const float*)d_in[1];
  const float* br = (const float*)d_in[2];
  const float* W1 = (const float*)d_in[3];
  const float* b1 = (const float*)d_in[4];
  const float* W2 = (const float*)d_in[5];
  const float* b2 = (const float*)d_in[6];
  float* out = (float*)d_out;

  const size_t SZ_W = (size_t)NEXP * DMODEL * DFF;  // 33.5M elems
  char* ws = (char*)d_ws;
  size_t o = 0;
  unsigned short* W1t = (unsigned short*)(ws + o); o += SZ_W * 2;                  // [E][DFF][DMODEL] bf16
  unsigned short* W2t = (unsigned short*)(ws + o); o += SZ_W * 2;                  // [E][DMODEL][DFF] bf16
  unsigned short* xb  = (unsigned short*)(ws + o); o += (size_t)TOKS * DMODEL * 2; // bf16 x
  unsigned short* h   = (unsigned short*)(ws + o); o += (size_t)2 * TOKS * DFF * 2;// bf16 h (8192 slots)
  int*   cnt   = (int*)(ws + o);   o += 256;
  int*   offp  = (int*)(ws + o);   o += 256;
  int*   list  = (int*)(ws + o);   o += (size_t)NEXP * TOKS * 4;
  float* plist = (float*)(ws + o); o += (size_t)NEXP * TOKS * 4;
  if (o > ws_size) {
    fprintf(stderr, "kernel_launch: ws too small: need %zu have %zu\n", o, ws_size);
    hipMemsetAsync(d_out, 0, (size_t)out_size * 4, stream);
    return;
  }

  hipMemsetAsync(cnt, 0, 256, stream);
  hipMemsetAsync(d_out, 0, (size_t)out_size * 4, stream);

  transpose_cast_k<<<dim3((DMODEL / 64) * (DFF / 64), NEXP), 256, 0, stream>>>(W1, W1t, DMODEL, DFF);
  transpose_cast_k<<<dim3((DFF / 64) * (DMODEL / 64), NEXP), 256, 0, stream>>>(W2, W2t, DFF, DMODEL);
  cast_x_k<<<TOKS * DMODEL / 4 / 256, 256, 0, stream>>>(x, xb);
  router_k<<<TOKS / 4, 256, 0, stream>>>(x, Wr, br, cnt, list, plist);
  offsets_k<<<1, 64, 0, stream>>>(cnt, offp);
  moe_gemm_k<0><<<dim3(DFF / 128, TOKS / 128, NEXP), 256, 0, stream>>>(
      xb, W1t, b1, cnt, offp, list, plist, h, nullptr);
  moe_gemm_k<1><<<dim3(DMODEL / 128, TOKS / 128, NEXP), 256, 0, stream>>>(
      h, W2t, b2, cnt, offp, list, plist, nullptr, out);
}

// Round 5
// 750.743 us; speedup vs baseline: 1.0225x; 1.0225x over previous
//
#include <hip/hip_runtime.h>
#include <cstdio>
#include <cstdint>

#define TOKS 4096
#define DMODEL 1024
#define DFF 4096
#define NEXP 8

typedef __bf16 bf16_8 __attribute__((ext_vector_type(8)));
typedef float f32x4 __attribute__((ext_vector_type(4)));
typedef __attribute__((address_space(1))) const void* gptr_t;
typedef __attribute__((address_space(3))) void* lptr_t;

__device__ __forceinline__ unsigned short f2bf(float f) {
  unsigned int u = __builtin_bit_cast(unsigned int, f);
  u += 0x7FFFu + ((u >> 16) & 1u);
  return (unsigned short)(u >> 16);
}

// ---------------- transpose + cast fp32 [R][C] -> bf16 [C][R], per-expert (blockIdx.y) ----
__global__ __launch_bounds__(256) void transpose_cast_k(const float* __restrict__ in,
                                                        unsigned short* __restrict__ out,
                                                        int R, int C) {
  __shared__ float tile[64][65];
  const float* inm = in + (size_t)blockIdx.y * R * C;
  unsigned short* outm = out + (size_t)blockIdx.y * R * C;
  int tcn = C >> 6;
  int tr = blockIdx.x / tcn, tc = blockIdx.x % tcn;
  int r0 = tr << 6, c0 = tc << 6;
  int tid = threadIdx.x;
  int lr = tid >> 6, lc = tid & 63;
#pragma unroll
  for (int i = 0; i < 16; ++i)
    tile[lr + 4 * i][lc] = inm[(size_t)(r0 + lr + 4 * i) * C + c0 + lc];
  __syncthreads();
#pragma unroll
  for (int i = 0; i < 8; ++i) {
    int row = (tid >> 5) + i * 8;  // out-row (c index) within tile
    int colu = tid & 31;           // uint column (2 bf16)
    float f0 = tile[colu * 2][row];
    float f1 = tile[colu * 2 + 1][row];
    unsigned int u = (unsigned int)f2bf(f0) | ((unsigned int)f2bf(f1) << 16);
    *(unsigned int*)(outm + (size_t)(c0 + row) * R + r0 + colu * 2) = u;
  }
}

// ---------------- cast x fp32 -> bf16 (vectorized) ----------------
__global__ __launch_bounds__(256) void cast_x_k(const float* __restrict__ x,
                                                unsigned short* __restrict__ xb) {
  int i = blockIdx.x * 256 + threadIdx.x;  // exactly TOKS*DMODEL/4 threads
  float4 f = ((const float4*)x)[i];
  ushort4 u;
  u.x = f2bf(f.x); u.y = f2bf(f.y); u.z = f2bf(f.z); u.w = f2bf(f.w);
  ((ushort4*)xb)[i] = u;
}

// ---------------- router: logits -> top2 -> probs -> expert lists ----------------
__global__ __launch_bounds__(256) void router_k(const float* __restrict__ x,
                                                const float* __restrict__ Wr,
                                                const float* __restrict__ br,
                                                int* __restrict__ cnt,
                                                int* __restrict__ list,
                                                float* __restrict__ plist) {
  int t = blockIdx.x * 4 + (threadIdx.x >> 6);
  int lane = threadIdx.x & 63;
  float a[NEXP];
#pragma unroll
  for (int e = 0; e < NEXP; ++e) a[e] = 0.f;
  const float* xr = x + (size_t)t * DMODEL;
  for (int i = lane; i < DMODEL; i += 64) {
    float xv = xr[i];
    const float* wr = Wr + (size_t)i * NEXP;
#pragma unroll
    for (int e = 0; e < NEXP; ++e) a[e] += xv * wr[e];
  }
#pragma unroll
  for (int off = 32; off > 0; off >>= 1) {
#pragma unroll
    for (int e = 0; e < NEXP; ++e) a[e] += __shfl_xor(a[e], off);
  }
  if (lane == 0) {
#pragma unroll
    for (int e = 0; e < NEXP; ++e) a[e] += br[e];
    int i0 = 0; float m0 = a[0];
#pragma unroll
    for (int e = 1; e < NEXP; ++e) if (a[e] > m0) { m0 = a[e]; i0 = e; }
    int i1 = -1; float m1 = -1e30f;
#pragma unroll
    for (int e = 0; e < NEXP; ++e) if (e != i0 && a[e] > m1) { m1 = a[e]; i1 = e; }
    float tt = expf(m1 - m0);
    float p0 = 1.f / (1.f + tt);
    float p1 = 1.f - p0;
    int pos0 = atomicAdd(&cnt[i0], 1);
    list[i0 * TOKS + pos0] = t; plist[i0 * TOKS + pos0] = p0;
    int pos1 = atomicAdd(&cnt[i1], 1);
    list[i1 * TOKS + pos1] = t; plist[i1 * TOKS + pos1] = p1;
  }
}

__global__ void offsets_k(const int* __restrict__ cnt, int* __restrict__ off) {
  if (threadIdx.x == 0) {
    int s = 0;
    for (int e = 0; e < NEXP; ++e) { off[e] = s; s += cnt[e]; }
    off[NEXP] = s;
  }
}

// ---------------- grouped GEMM, 128x128 tile, BK=64, bf16 MFMA 16x16x32 ----------------
// 2-phase double-buffered pipeline (T3 minimum recipe) + XCD-chunked swizzle (T1):
// one expert per XCD, n-tile fastest within expert -> B slab streams once per XCD,
// A-tile L2-resident across its 32 (or 8) n-tiles.
// MODE 0: A = xb rows gathered via list  [K=1024], B = W1t [DFF][1024], out: h=relu(.+b1) bf16
// MODE 1: A = h rows (compact slots)     [K=4096], B = W2t [DMODEL][4096], out: atomicAdd p*(.+b2)
template <int MODE>
__global__ __launch_bounds__(256) void moe_gemm_k(
    const unsigned short* __restrict__ Abase, const unsigned short* __restrict__ Bbase,
    const float* __restrict__ bias, const int* __restrict__ cnt, const int* __restrict__ off,
    const int* __restrict__ list, const float* __restrict__ plist,
    unsigned short* __restrict__ Hout, float* __restrict__ Out) {
  constexpr int K = (MODE == 0) ? DMODEL : DFF;
  constexpr int NN = (MODE == 0) ? DFF : DMODEL;
  constexpr int NT = NN / 128;          // n-tiles
  constexpr int NWG = NEXP * 32 * NT;   // total blocks (%8 == 0)
  constexpr int CHUNK = NWG / 8;

  // bijective XCD swizzle: flat dispatch id -> chunked id u, decoded nt-fastest
  const int flat = blockIdx.x + NT * (blockIdx.y + 32 * blockIdx.z);
  const int u = (flat & 7) * CHUNK + (flat >> 3);
  const int nt = u % NT;
  const int mt = (u / NT) & 31;
  const int e = u / (NT * 32);

  const int ce = cnt[e];
  const int m0 = mt * 128;
  if (m0 >= ce) return;                 // empty tile (block-uniform) -> cheap exit
  const int rem = ce - m0;              // >= 1
  const int n0 = nt * 128;
  const int oe = off[e];

  __shared__ unsigned short As[2][8192];  // 128 rows x 64 k, XOR-swizzled 16B slots
  __shared__ unsigned short Bs[2][8192];

  const int tid = threadIdx.x;
  const int lane = tid & 63;
  const int w = tid >> 6;
  const int wm = w >> 1, wn = w & 1;

  const unsigned short* Bm = Bbase + (size_t)e * NN * K;
  // staging: physical 16B slot s = c*256+tid; row = s>>3; logical k-group = (s&7)^(row&7)
  const int g = (tid & 7) ^ ((tid >> 3) & 7);

  size_t a_src[4], b_src[4];
#pragma unroll
  for (int c = 0; c < 4; ++c) {
    int row = c * 32 + (tid >> 3);
    int rr = row < rem ? row : 0;       // clamp padding rows to a valid row
    size_t arow;
    if (MODE == 0) arow = (size_t)list[e * TOKS + m0 + rr];
    else           arow = (size_t)(oe + m0 + rr);
    a_src[c] = arow * K + g * 8;
    b_src[c] = (size_t)(n0 + row) * K + g * 8;
  }

  f32x4 acc[4][4];
#pragma unroll
  for (int i = 0; i < 4; ++i)
#pragma unroll
    for (int j = 0; j < 4; ++j) acc[i][j] = (f32x4){0.f, 0.f, 0.f, 0.f};

  auto STAGE = [&](int buf, int k0) {
#pragma unroll
    for (int c = 0; c < 4; ++c) {
      __builtin_amdgcn_global_load_lds((gptr_t)(Abase + a_src[c] + k0),
                                       (lptr_t)&As[buf][(c * 256 + w * 64) * 8], 16, 0, 0);
      __builtin_amdgcn_global_load_lds((gptr_t)(Bm + b_src[c] + k0),
                                       (lptr_t)&Bs[buf][(c * 256 + w * 64) * 8], 16, 0, 0);
    }
  };

  auto COMPUTE = [&](int buf) {
#pragma unroll
    for (int kk = 0; kk < 2; ++kk) {
      bf16_8 av[4], bv[4];
#pragma unroll
      for (int fr = 0; fr < 4; ++fr) {
        int row = wm * 64 + fr * 16 + (lane & 15);
        int slot = row * 8 + ((kk * 4 + (lane >> 4)) ^ (row & 7));
        av[fr] = *(const bf16_8*)&As[buf][slot * 8];
      }
#pragma unroll
      for (int fc = 0; fc < 4; ++fc) {
        int row = wn * 64 + fc * 16 + (lane & 15);
        int slot = row * 8 + ((kk * 4 + (lane >> 4)) ^ (row & 7));
        bv[fc] = *(const bf16_8*)&Bs[buf][slot * 8];
      }
#pragma unroll
      for (int fr = 0; fr < 4; ++fr)
#pragma unroll
        for (int fc = 0; fc < 4; ++fc)
          acc[fr][fc] = __builtin_amdgcn_mfma_f32_16x16x32_bf16(av[fr], bv[fc],
                                                                acc[fr][fc], 0, 0, 0);
    }
  };

  constexpr int NSTEP = K / 64;
  // prologue: stage tile 0
  STAGE(0, 0);
  __syncthreads();                      // compiler drains vmcnt before barrier
  int cur = 0;
  for (int t = 0; t < NSTEP - 1; ++t) {
    STAGE(cur ^ 1, (t + 1) * 64);       // prefetch next tile (overlaps with compute)
    COMPUTE(cur);
    __syncthreads();                    // vmcnt(0)+barrier: staged buf ready, reads done
    cur ^= 1;
  }
  COMPUTE(cur);                         // last tile, no prefetch

  if (MODE == 0) {
    const float* be = bias + (size_t)e * NN + n0;
#pragma unroll
    for (int fr = 0; fr < 4; ++fr) {
#pragma unroll
      for (int j = 0; j < 4; ++j) {
        int row = wm * 64 + fr * 16 + (lane >> 4) * 4 + j;
        if (row < rem) {
          unsigned short* hr = Hout + (size_t)(oe + m0 + row) * DFF + n0;
#pragma unroll
          for (int fc = 0; fc < 4; ++fc) {
            int col = wn * 64 + fc * 16 + (lane & 15);
            float v = acc[fr][fc][j] + be[col];
            hr[col] = f2bf(fmaxf(v, 0.f));
          }
        }
      }
    }
  } else {
    const float* be = bias + (size_t)e * NN + n0;
#pragma unroll
    for (int fr = 0; fr < 4; ++fr) {
#pragma unroll
      for (int j = 0; j < 4; ++j) {
        int row = wm * 64 + fr * 16 + (lane >> 4) * 4 + j;
        if (row < rem) {
          int tok = list[e * TOKS + m0 + row];
          float p = plist[e * TOKS + m0 + row];
          float* orow = Out + (size_t)tok * DMODEL + n0;
#pragma unroll
          for (int fc = 0; fc < 4; ++fc) {
            int col = wn * 64 + fc * 16 + (lane & 15);
            atomicAdd(&orow[col], p * (acc[fr][fc][j] + be[col]));
          }
        }
      }
    }
  }
}

extern "C" void kernel_launch(void* const* d_in, const int* in_sizes, int n_in,
                              void* d_out, int out_size, void* d_ws, size_t ws_size,
                              hipStream_t stream) {
  const float* x  = (const float*)d_in[0];
  const float* Wr = (const float*)d_in[1];
  const float* br = (const float*)d_in[2];
  const float* W1 = (const float*)d_in[3];
  const float* b1 = (const float*)d_in[4];
  const float* W2 = (const float*)d_in[5];
  const float* b2 = (const float*)d_in[6];
  float* out = (float*)d_out;

  const size_t SZ_W = (size_t)NEXP * DMODEL * DFF;  // 33.5M elems
  char* ws = (char*)d_ws;
  size_t o = 0;
  unsigned short* W1t = (unsigned short*)(ws + o); o += SZ_W * 2;                  // [E][DFF][DMODEL] bf16
  unsigned short* W2t = (unsigned short*)(ws + o); o += SZ_W * 2;                  // [E][DMODEL][DFF] bf16
  unsigned short* xb  = (unsigned short*)(ws + o); o += (size_t)TOKS * DMODEL * 2; // bf16 x
  unsigned short* h   = (unsigned short*)(ws + o); o += (size_t)2 * TOKS * DFF * 2;// bf16 h (8192 slots)
  int*   cnt   = (int*)(ws + o);   o += 256;
  int*   offp  = (int*)(ws + o);   o += 256;
  int*   list  = (int*)(ws + o);   o += (size_t)NEXP * TOKS * 4;
  float* plist = (float*)(ws + o); o += (size_t)NEXP * TOKS * 4;
  if (o > ws_size) {
    fprintf(stderr, "kernel_launch: ws too small: need %zu have %zu\n", o, ws_size);
    hipMemsetAsync(d_out, 0, (size_t)out_size * 4, stream);
    return;
  }

  hipMemsetAsync(cnt, 0, 256, stream);
  hipMemsetAsync(d_out, 0, (size_t)out_size * 4, stream);

  transpose_cast_k<<<dim3((DMODEL / 64) * (DFF / 64), NEXP), 256, 0, stream>>>(W1, W1t, DMODEL, DFF);
  transpose_cast_k<<<dim3((DFF / 64) * (DMODEL / 64), NEXP), 256, 0, stream>>>(W2, W2t, DFF, DMODEL);
  cast_x_k<<<TOKS * DMODEL / 4 / 256, 256, 0, stream>>>(x, xb);
  router_k<<<TOKS / 4, 256, 0, stream>>>(x, Wr, br, cnt, list, plist);
  offsets_k<<<1, 64, 0, stream>>>(cnt, offp);
  moe_gemm_k<0><<<dim3(DFF / 128, TOKS / 128, NEXP), 256, 0, stream>>>(
      xb, W1t, b1, cnt, offp, list, plist, h, nullptr);
  moe_gemm_k<1><<<dim3(DMODEL / 128, TOKS / 128, NEXP), 256, 0, stream>>>(
      h, W2t, b2, cnt, offp, list, plist, nullptr, out);
}